// Round 1
// baseline (1706.826 us; speedup 1.0000x reference)
//
#include <hip/hip_runtime.h>
#include <hip/hip_bf16.h>
#include <math.h>

#define B_BATCH   1024
#define D_DIM     512
#define C_CLASSES 100000
#define BM        128
#define BN        128
#define BK        32
#define KITERS    (D_DIM / BK)                    // 16
#define NTILES    ((C_CLASSES + BN - 1) / BN)     // 782
#define LDS_STRIDE 40                             // 32 + 8 pad -> conflict-free frag reads
#define LOG2E     1.44269504088896340736f
#define PI_F      3.14159265358979323846f
#define NEG_LOG_EPS 69.07755278982137f            // -ln(1e-30)

typedef short bf16x8 __attribute__((ext_vector_type(8)));
typedef float f32x4  __attribute__((ext_vector_type(4)));
typedef unsigned short u16x8 __attribute__((ext_vector_type(8)));

static __device__ __forceinline__ unsigned short f2bf(float f) {
    unsigned int u = __builtin_bit_cast(unsigned int, f);
    u += 0x7fffu + ((u >> 16) & 1u);              // round-to-nearest-even
    return (unsigned short)(u >> 16);
}

// ---------------- kernel 1: normalize embeddings -> bf16 A [1024 x 512] ---
__global__ __launch_bounds__(256) void norm_embed(const float* __restrict__ E,
                                                  unsigned short* __restrict__ Abf) {
    const int b = blockIdx.x;
    const int t = threadIdx.x;
    float2 v = ((const float2*)(E + (size_t)b * D_DIM))[t];
    float ss = v.x * v.x + v.y * v.y;
    #pragma unroll
    for (int off = 1; off < 64; off <<= 1) ss += __shfl_xor(ss, off);
    __shared__ float ws4[4];
    if ((t & 63) == 0) ws4[t >> 6] = ss;
    __syncthreads();
    float inv = rsqrtf(ws4[0] + ws4[1] + ws4[2] + ws4[3]);
    unsigned int packed = (unsigned int)f2bf(v.x * inv) |
                          ((unsigned int)f2bf(v.y * inv) << 16);
    ((unsigned int*)Abf)[(size_t)b * (D_DIM / 2) + t] = packed;
}

// ---------------- kernel 2: fused GEMM + weight-norm + margin + partial softmax
__global__ __launch_bounds__(256) void gemm_pfc(const unsigned short* __restrict__ Abf,
                                                const float* __restrict__ W,
                                                const int* __restrict__ labels,
                                                float* __restrict__ st,
                                                float* __restrict__ partial) {
    __shared__ unsigned short As[BM * LDS_STRIDE];
    __shared__ unsigned short Bs[BN * LDS_STRIDE];
    __shared__ float invN[BN];
    __shared__ float rowSum[BM];
    __shared__ float nrmPart[256];
    __shared__ int   labs[BM];

    const int tid = threadIdx.x;
    const int n0 = blockIdx.x * BN;
    const int m0 = blockIdx.y * BM;

    if (tid < BM) { labs[tid] = labels[m0 + tid]; rowSum[tid] = 0.f; }

    const int lane = tid & 63;
    const int wave = tid >> 6;
    const int wm = wave & 1, wn = wave >> 1;
    const int l15 = lane & 15, quad = lane >> 4;

    f32x4 acc[4][4];
    #pragma unroll
    for (int i = 0; i < 4; ++i)
        #pragma unroll
        for (int j = 0; j < 4; ++j)
            acc[i][j] = (f32x4){0.f, 0.f, 0.f, 0.f};

    // staging assignment: thread -> (row r2 of tile, k-half h2)
    const int r2 = tid >> 1;
    const int h2 = tid & 1;
    const int bRow = min(n0 + r2, C_CLASSES - 1);
    const float* bBase = W + (size_t)bRow * D_DIM + h2 * 16;
    const unsigned short* aBase = Abf + (size_t)(m0 + r2) * D_DIM + h2 * 16;

    float nrm = 0.f;

    for (int kk = 0; kk < KITERS; ++kk) {
        const int k0 = kk * BK;
        // ---- global loads (A: 16 bf16, B: 16 fp32) ----
        uint4 a0 = ((const uint4*)(aBase + k0))[0];
        uint4 a1 = ((const uint4*)(aBase + k0))[1];
        float4 f0 = ((const float4*)(bBase + k0))[0];
        float4 f1 = ((const float4*)(bBase + k0))[1];
        float4 f2 = ((const float4*)(bBase + k0))[2];
        float4 f3 = ((const float4*)(bBase + k0))[3];
        float fl[16] = {f0.x, f0.y, f0.z, f0.w, f1.x, f1.y, f1.z, f1.w,
                        f2.x, f2.y, f2.z, f2.w, f3.x, f3.y, f3.z, f3.w};
        u16x8 p0, p1;
        #pragma unroll
        for (int i = 0; i < 8; ++i) {
            nrm += fl[i] * fl[i] + fl[i + 8] * fl[i + 8];
            p0[i] = f2bf(fl[i]);
            p1[i] = f2bf(fl[i + 8]);
        }

        __syncthreads();   // previous iteration's fragment reads done
        *(uint4*)&As[r2 * LDS_STRIDE + h2 * 16]     = a0;
        *(uint4*)&As[r2 * LDS_STRIDE + h2 * 16 + 8] = a1;
        *(u16x8*)&Bs[r2 * LDS_STRIDE + h2 * 16]     = p0;
        *(u16x8*)&Bs[r2 * LDS_STRIDE + h2 * 16 + 8] = p1;
        __syncthreads();

        bf16x8 af[4], bf[4];
        #pragma unroll
        for (int mi = 0; mi < 4; ++mi)
            af[mi] = *(const bf16x8*)&As[(wm * 64 + mi * 16 + l15) * LDS_STRIDE + quad * 8];
        #pragma unroll
        for (int ni = 0; ni < 4; ++ni)
            bf[ni] = *(const bf16x8*)&Bs[(wn * 64 + ni * 16 + l15) * LDS_STRIDE + quad * 8];
        #pragma unroll
        for (int mi = 0; mi < 4; ++mi)
            #pragma unroll
            for (int ni = 0; ni < 4; ++ni)
                acc[mi][ni] = __builtin_amdgcn_mfma_f32_16x16x32_bf16(af[mi], bf[ni], acc[mi][ni], 0, 0, 0);
    }

    // ---- column inverse norms (from bf16-rounded fp32 squares, fp32 accum) ----
    nrmPart[tid] = nrm;
    __syncthreads();
    if (tid < BN) invN[tid] = rsqrtf(nrmPart[2 * tid] + nrmPart[2 * tid + 1]);
    __syncthreads();

    // ---- epilogue: cos -> clip -> margin at label -> sum exp(s-64) per row ----
    float rn[4];
    #pragma unroll
    for (int ni = 0; ni < 4; ++ni) rn[ni] = invN[wn * 64 + ni * 16 + l15];

    #pragma unroll
    for (int mi = 0; mi < 4; ++mi) {
        #pragma unroll
        for (int r = 0; r < 4; ++r) {
            const int rloc = wm * 64 + mi * 16 + quad * 4 + r;
            const int lab = labs[rloc];
            float part = 0.f;
            #pragma unroll
            for (int ni = 0; ni < 4; ++ni) {
                const int cg = n0 + wn * 64 + ni * 16 + l15;
                float cosv = acc[mi][ni][r] * rn[ni];
                cosv = fminf(1.f, fmaxf(-1.f, cosv));
                if (cg < C_CLASSES) {
                    float s = cosv * 64.0f;
                    if (cg == lab) {
                        float th = acosf(cosv);
                        s = cosf(fminf(th + 0.5f, PI_F)) * 64.0f;
                        st[m0 + rloc] = s;   // unique writer
                    }
                    part += exp2f((s - 64.0f) * LOG2E);
                }
            }
            part += __shfl_xor(part, 1);
            part += __shfl_xor(part, 2);
            part += __shfl_xor(part, 4);
            part += __shfl_xor(part, 8);
            if (l15 == 0) atomicAdd(&rowSum[rloc], part);
        }
    }
    __syncthreads();
    if (tid < BM) partial[(size_t)blockIdx.x * B_BATCH + m0 + tid] = rowSum[tid];
}

// ---------------- kernel 3: per-row combine + mean loss ----------------
__global__ __launch_bounds__(256) void reduce_loss(const float* __restrict__ partial,
                                                   const float* __restrict__ st,
                                                   float* __restrict__ out) {
    const int b = blockIdx.x * 256 + threadIdx.x;
    if (b < B_BATCH) {
        float L = 0.f;
        for (int t = 0; t < NTILES; ++t) L += partial[(size_t)t * B_BATCH + b];
        float logp = st[b] - 64.0f - logf(L);
        float lossb = fminf(-logp, NEG_LOG_EPS);
        atomicAdd(out, lossb * (1.0f / (float)B_BATCH));
    }
}

extern "C" void kernel_launch(void* const* d_in, const int* in_sizes, int n_in,
                              void* d_out, int out_size, void* d_ws, size_t ws_size,
                              hipStream_t stream) {
    const float* emb = (const float*)d_in[0];
    const float* wgt = (const float*)d_in[1];
    const int*   lab = (const int*)d_in[2];
    float* out = (float*)d_out;

    char* ws = (char*)d_ws;
    unsigned short* Abf = (unsigned short*)ws;                       // 1 MiB
    float* st      = (float*)(ws + (size_t)B_BATCH * D_DIM * 2);     // 4 KiB
    float* partial = (float*)(ws + (size_t)B_BATCH * D_DIM * 2 + 4096);  // 782*1024*4 B

    hipMemsetAsync(d_out, 0, sizeof(float), stream);
    norm_embed<<<B_BATCH, 256, 0, stream>>>(emb, Abf);
    gemm_pfc<<<dim3(NTILES, B_BATCH / BM), 256, 0, stream>>>(Abf, wgt, lab, st, partial);
    reduce_loss<<<4, 256, 0, stream>>>(partial, st, out);
}

// Round 2
// 1500.531 us; speedup vs baseline: 1.1375x; 1.1375x over previous
//
#include <hip/hip_runtime.h>
#include <hip/hip_bf16.h>
#include <math.h>
#include <stdint.h>

#define B_BATCH   1024
#define D_DIM     512
#define C_CLASSES 100000
#define BM        128
#define BN        128
#define BK        32
#define KITERS    (D_DIM / BK)                    // 16
#define NTILES    ((C_CLASSES + BN - 1) / BN)     // 782
#define LOG2E     1.44269504088896340736f
#define PI_F      3.14159265358979323846f
#define NEG_LOG_EPS 69.07755278982137f            // -ln(1e-30)

typedef short bf16x8 __attribute__((ext_vector_type(8)));
typedef float f32x4  __attribute__((ext_vector_type(4)));
typedef unsigned short u16x8 __attribute__((ext_vector_type(8)));

static __device__ __forceinline__ unsigned short f2bf(float f) {
    unsigned int u = __builtin_bit_cast(unsigned int, f);
    u += 0x7fffu + ((u >> 16) & 1u);              // round-to-nearest-even
    return (unsigned short)(u >> 16);
}

// async 16B global -> LDS (wave-uniform LDS base + lane*16 implicit)
static __device__ __forceinline__ void gld16(const unsigned short* g, unsigned short* l) {
    __builtin_amdgcn_global_load_lds(
        (const __attribute__((address_space(1))) unsigned int*)g,
        (__attribute__((address_space(3))) unsigned int*)l, 16, 0, 0);
}

// ---------------- kernel 1: normalize embeddings -> bf16 A [1024 x 512] ---
__global__ __launch_bounds__(256) void norm_embed(const float* __restrict__ E,
                                                  unsigned short* __restrict__ Abf) {
    const int b = blockIdx.x;
    const int t = threadIdx.x;
    float2 v = ((const float2*)(E + (size_t)b * D_DIM))[t];
    float ss = v.x * v.x + v.y * v.y;
    #pragma unroll
    for (int off = 1; off < 64; off <<= 1) ss += __shfl_xor(ss, off);
    __shared__ float ws4[4];
    if ((t & 63) == 0) ws4[t >> 6] = ss;
    __syncthreads();
    float inv = rsqrtf(ws4[0] + ws4[1] + ws4[2] + ws4[3]);
    unsigned int packed = (unsigned int)f2bf(v.x * inv) |
                          ((unsigned int)f2bf(v.y * inv) << 16);
    ((unsigned int*)Abf)[(size_t)b * (D_DIM / 2) + t] = packed;
}

// ---------------- kernel 1b: normalize weights -> bf16 [C x 512] ----------
// one wave per row; lane reads 2x float4, writes 2x (4 bf16)
__global__ __launch_bounds__(256) void norm_weight(const float* __restrict__ W,
                                                   unsigned short* __restrict__ Wbf) {
    const int wave = threadIdx.x >> 6;
    const int lane = threadIdx.x & 63;
    const int row = blockIdx.x * 4 + wave;
    if (row >= C_CLASSES) return;
    const float4* src = (const float4*)(W + (size_t)row * D_DIM);
    float4 v0 = src[lane];
    float4 v1 = src[lane + 64];
    float ss = v0.x*v0.x + v0.y*v0.y + v0.z*v0.z + v0.w*v0.w
             + v1.x*v1.x + v1.y*v1.y + v1.z*v1.z + v1.w*v1.w;
    #pragma unroll
    for (int off = 1; off < 64; off <<= 1) ss += __shfl_xor(ss, off);
    float inv = rsqrtf(ss);
    ushort4 o0, o1;
    o0.x = f2bf(v0.x*inv); o0.y = f2bf(v0.y*inv); o0.z = f2bf(v0.z*inv); o0.w = f2bf(v0.w*inv);
    o1.x = f2bf(v1.x*inv); o1.y = f2bf(v1.y*inv); o1.z = f2bf(v1.z*inv); o1.w = f2bf(v1.w*inv);
    ushort4* dst = (ushort4*)(Wbf + (size_t)row * D_DIM);
    dst[lane] = o0;
    dst[lane + 64] = o1;
}

// ---------------- kernel 2: bf16 GEMM (cosine logits) + margin + partial softmax
__global__ __launch_bounds__(256) void gemm_cos(const unsigned short* __restrict__ Abf,
                                                const unsigned short* __restrict__ Wbf,
                                                const int* __restrict__ labels,
                                                float* __restrict__ st,
                                                float* __restrict__ partial) {
    __shared__ unsigned short As[BM * BK];   // 8 KiB, unpadded (global_load_lds layout)
    __shared__ unsigned short Bs[BN * BK];   // 8 KiB
    __shared__ float rowSum[BM];
    __shared__ int   labs[BM];

    const int tid = threadIdx.x;
    const int n0 = blockIdx.x * BN;
    const int m0 = blockIdx.y * BM;
    if (tid < BM) { labs[tid] = labels[m0 + tid]; rowSum[tid] = 0.f; }

    const int lane = tid & 63;
    const int wave = tid >> 6;
    const int wm = wave & 1, wn = wave >> 1;
    const int l15 = lane & 15, quad = lane >> 4;

    // staging: wave w stages chunks (2w) and (2w+1) of both tiles.
    // chunk c = rows [16c, 16c+16); lane i -> row 16c + (i>>2), col 8*(i&3).
    const int rsub = lane >> 2;
    const int cg   = (lane & 3) * 8;
    const int c0 = wave * 2, c1 = wave * 2 + 1;
    const unsigned short* gA0 = Abf + (size_t)(m0 + c0 * 16 + rsub) * D_DIM + cg;
    const unsigned short* gA1 = Abf + (size_t)(m0 + c1 * 16 + rsub) * D_DIM + cg;
    const int bR0 = min(n0 + c0 * 16 + rsub, C_CLASSES - 1);
    const int bR1 = min(n0 + c1 * 16 + rsub, C_CLASSES - 1);
    const unsigned short* gB0 = Wbf + (size_t)bR0 * D_DIM + cg;
    const unsigned short* gB1 = Wbf + (size_t)bR1 * D_DIM + cg;
    unsigned short* lA0 = &As[c0 * 512];    // 1024 B per chunk
    unsigned short* lA1 = &As[c1 * 512];
    unsigned short* lB0 = &Bs[c0 * 512];
    unsigned short* lB1 = &Bs[c1 * 512];

    f32x4 acc[4][4];
    #pragma unroll
    for (int i = 0; i < 4; ++i)
        #pragma unroll
        for (int j = 0; j < 4; ++j)
            acc[i][j] = (f32x4){0.f, 0.f, 0.f, 0.f};

    for (int kk = 0; kk < KITERS; ++kk) {
        __syncthreads();                     // prior frag reads done
        gld16(gA0, lA0); gld16(gA1, lA1);
        gld16(gB0, lB0); gld16(gB1, lB1);
        gA0 += BK; gA1 += BK; gB0 += BK; gB1 += BK;
        __syncthreads();                     // loads visible (vmcnt drained)

        bf16x8 af[4], bfr[4];
        #pragma unroll
        for (int mi = 0; mi < 4; ++mi)
            af[mi] = *(const bf16x8*)&As[(wm * 64 + mi * 16 + l15) * BK + quad * 8];
        #pragma unroll
        for (int ni = 0; ni < 4; ++ni)
            bfr[ni] = *(const bf16x8*)&Bs[(wn * 64 + ni * 16 + l15) * BK + quad * 8];
        #pragma unroll
        for (int mi = 0; mi < 4; ++mi)
            #pragma unroll
            for (int ni = 0; ni < 4; ++ni)
                acc[mi][ni] = __builtin_amdgcn_mfma_f32_16x16x32_bf16(af[mi], bfr[ni], acc[mi][ni], 0, 0, 0);
    }

    // ---- epilogue: clip -> margin at label -> sum exp(s-64) per row ----
    #pragma unroll
    for (int mi = 0; mi < 4; ++mi) {
        #pragma unroll
        for (int r = 0; r < 4; ++r) {
            const int rloc = wm * 64 + mi * 16 + quad * 4 + r;
            const int lab = labs[rloc];
            float part = 0.f;
            #pragma unroll
            for (int ni = 0; ni < 4; ++ni) {
                const int col = n0 + wn * 64 + ni * 16 + l15;
                float cosv = fminf(1.f, fmaxf(-1.f, acc[mi][ni][r]));
                if (col < C_CLASSES) {
                    float s = cosv * 64.0f;
                    if (col == lab) {
                        s = cosf(fminf(acosf(cosv) + 0.5f, PI_F)) * 64.0f;
                        st[m0 + rloc] = s;   // unique writer across grid
                    }
                    part += exp2f((s - 64.0f) * LOG2E);
                }
            }
            part += __shfl_xor(part, 1);
            part += __shfl_xor(part, 2);
            part += __shfl_xor(part, 4);
            part += __shfl_xor(part, 8);
            if (l15 == 0) atomicAdd(&rowSum[rloc], part);
        }
    }
    __syncthreads();
    if (tid < BM) partial[(size_t)blockIdx.x * B_BATCH + m0 + tid] = rowSum[tid];
}

// ---------------- kernel 3: per-row combine + mean loss ----------------
__global__ __launch_bounds__(256) void reduce_loss(const float* __restrict__ partial,
                                                   const float* __restrict__ st,
                                                   float* __restrict__ out) {
    const int b = blockIdx.x * 256 + threadIdx.x;
    if (b < B_BATCH) {
        float L = 0.f;
        for (int t = 0; t < NTILES; ++t) L += partial[(size_t)t * B_BATCH + b];
        float logp = st[b] - 64.0f - logf(L);
        float lossb = fminf(-logp, NEG_LOG_EPS);
        atomicAdd(out, lossb * (1.0f / (float)B_BATCH));
    }
}

// ================= fallback (round-1 fused, needs only ~4.3 MB ws) =========
#define LDS_STRIDE 40
__global__ __launch_bounds__(256) void gemm_pfc(const unsigned short* __restrict__ Abf,
                                                const float* __restrict__ W,
                                                const int* __restrict__ labels,
                                                float* __restrict__ st,
                                                float* __restrict__ partial) {
    __shared__ unsigned short As[BM * LDS_STRIDE];
    __shared__ unsigned short Bs[BN * LDS_STRIDE];
    __shared__ float invN[BN];
    __shared__ float rowSum[BM];
    __shared__ float nrmPart[256];
    __shared__ int   labs[BM];

    const int tid = threadIdx.x;
    const int n0 = blockIdx.x * BN;
    const int m0 = blockIdx.y * BM;
    if (tid < BM) { labs[tid] = labels[m0 + tid]; rowSum[tid] = 0.f; }

    const int lane = tid & 63;
    const int wave = tid >> 6;
    const int wm = wave & 1, wn = wave >> 1;
    const int l15 = lane & 15, quad = lane >> 4;

    f32x4 acc[4][4];
    #pragma unroll
    for (int i = 0; i < 4; ++i)
        #pragma unroll
        for (int j = 0; j < 4; ++j)
            acc[i][j] = (f32x4){0.f, 0.f, 0.f, 0.f};

    const int r2 = tid >> 1;
    const int h2 = tid & 1;
    const int bRow = min(n0 + r2, C_CLASSES - 1);
    const float* bBase = W + (size_t)bRow * D_DIM + h2 * 16;
    const unsigned short* aBase = Abf + (size_t)(m0 + r2) * D_DIM + h2 * 16;

    float nrm = 0.f;
    for (int kk = 0; kk < KITERS; ++kk) {
        const int k0 = kk * BK;
        uint4 a0 = ((const uint4*)(aBase + k0))[0];
        uint4 a1 = ((const uint4*)(aBase + k0))[1];
        float4 f0 = ((const float4*)(bBase + k0))[0];
        float4 f1 = ((const float4*)(bBase + k0))[1];
        float4 f2 = ((const float4*)(bBase + k0))[2];
        float4 f3 = ((const float4*)(bBase + k0))[3];
        float fl[16] = {f0.x, f0.y, f0.z, f0.w, f1.x, f1.y, f1.z, f1.w,
                        f2.x, f2.y, f2.z, f2.w, f3.x, f3.y, f3.z, f3.w};
        u16x8 p0, p1;
        #pragma unroll
        for (int i = 0; i < 8; ++i) {
            nrm += fl[i] * fl[i] + fl[i + 8] * fl[i + 8];
            p0[i] = f2bf(fl[i]);
            p1[i] = f2bf(fl[i + 8]);
        }
        __syncthreads();
        *(uint4*)&As[r2 * LDS_STRIDE + h2 * 16]     = a0;
        *(uint4*)&As[r2 * LDS_STRIDE + h2 * 16 + 8] = a1;
        *(u16x8*)&Bs[r2 * LDS_STRIDE + h2 * 16]     = p0;
        *(u16x8*)&Bs[r2 * LDS_STRIDE + h2 * 16 + 8] = p1;
        __syncthreads();
        bf16x8 af[4], bfr[4];
        #pragma unroll
        for (int mi = 0; mi < 4; ++mi)
            af[mi] = *(const bf16x8*)&As[(wm * 64 + mi * 16 + l15) * LDS_STRIDE + quad * 8];
        #pragma unroll
        for (int ni = 0; ni < 4; ++ni)
            bfr[ni] = *(const bf16x8*)&Bs[(wn * 64 + ni * 16 + l15) * LDS_STRIDE + quad * 8];
        #pragma unroll
        for (int mi = 0; mi < 4; ++mi)
            #pragma unroll
            for (int ni = 0; ni < 4; ++ni)
                acc[mi][ni] = __builtin_amdgcn_mfma_f32_16x16x32_bf16(af[mi], bfr[ni], acc[mi][ni], 0, 0, 0);
    }
    nrmPart[tid] = nrm;
    __syncthreads();
    if (tid < BN) invN[tid] = rsqrtf(nrmPart[2 * tid] + nrmPart[2 * tid + 1]);
    __syncthreads();
    float rn[4];
    #pragma unroll
    for (int ni = 0; ni < 4; ++ni) rn[ni] = invN[wn * 64 + ni * 16 + l15];
    #pragma unroll
    for (int mi = 0; mi < 4; ++mi) {
        #pragma unroll
        for (int r = 0; r < 4; ++r) {
            const int rloc = wm * 64 + mi * 16 + quad * 4 + r;
            const int lab = labs[rloc];
            float part = 0.f;
            #pragma unroll
            for (int ni = 0; ni < 4; ++ni) {
                const int col = n0 + wn * 64 + ni * 16 + l15;
                float cosv = acc[mi][ni][r] * rn[ni];
                cosv = fminf(1.f, fmaxf(-1.f, cosv));
                if (col < C_CLASSES) {
                    float s = cosv * 64.0f;
                    if (col == lab) {
                        s = cosf(fminf(acosf(cosv) + 0.5f, PI_F)) * 64.0f;
                        st[m0 + rloc] = s;
                    }
                    part += exp2f((s - 64.0f) * LOG2E);
                }
            }
            part += __shfl_xor(part, 1);
            part += __shfl_xor(part, 2);
            part += __shfl_xor(part, 4);
            part += __shfl_xor(part, 8);
            if (l15 == 0) atomicAdd(&rowSum[rloc], part);
        }
    }
    __syncthreads();
    if (tid < BM) partial[(size_t)blockIdx.x * B_BATCH + m0 + tid] = rowSum[tid];
}

extern "C" void kernel_launch(void* const* d_in, const int* in_sizes, int n_in,
                              void* d_out, int out_size, void* d_ws, size_t ws_size,
                              hipStream_t stream) {
    const float* emb = (const float*)d_in[0];
    const float* wgt = (const float*)d_in[1];
    const int*   lab = (const int*)d_in[2];
    float* out = (float*)d_out;
    char* ws = (char*)d_ws;

    const size_t WBF_B  = (size_t)C_CLASSES * D_DIM * 2;  // 102,400,000
    const size_t ABF_B  = (size_t)B_BATCH * D_DIM * 2;    // 1,048,576
    const size_t ST_B   = 4096;
    const size_t PART_B = (size_t)NTILES * B_BATCH * 4;   // 3,203,072

    hipMemsetAsync(d_out, 0, sizeof(float), stream);

    if (ws_size >= WBF_B + ABF_B + ST_B + PART_B) {
        unsigned short* Wbf = (unsigned short*)ws;
        unsigned short* Abf = (unsigned short*)(ws + WBF_B);
        float* st      = (float*)(ws + WBF_B + ABF_B);
        float* partial = (float*)(ws + WBF_B + ABF_B + ST_B);
        norm_embed<<<B_BATCH, 256, 0, stream>>>(emb, Abf);
        norm_weight<<<(C_CLASSES + 3) / 4, 256, 0, stream>>>(wgt, Wbf);
        gemm_cos<<<dim3(NTILES, B_BATCH / BM), 256, 0, stream>>>(Abf, Wbf, lab, st, partial);
        reduce_loss<<<4, 256, 0, stream>>>(partial, st, out);
    } else {
        unsigned short* Abf = (unsigned short*)ws;
        float* st      = (float*)(ws + ABF_B);
        float* partial = (float*)(ws + ABF_B + ST_B);
        norm_embed<<<B_BATCH, 256, 0, stream>>>(emb, Abf);
        gemm_pfc<<<dim3(NTILES, B_BATCH / BM), 256, 0, stream>>>(Abf, wgt, lab, st, partial);
        reduce_loss<<<4, 256, 0, stream>>>(partial, st, out);
    }
}

// Round 3
// 1444.187 us; speedup vs baseline: 1.1819x; 1.0390x over previous
//
#include <hip/hip_runtime.h>
#include <hip/hip_bf16.h>
#include <math.h>
#include <stdint.h>

#define B_BATCH   1024
#define D_DIM     512
#define C_CLASSES 100000
#define BM        128
#define BN        128
#define BK        32
#define KITERS    (D_DIM / BK)                    // 16
#define MTILES    (B_BATCH / BM)                  // 8
#define NTILES    ((C_CLASSES + BN - 1) / BN)     // 782
#define LOG2E     1.44269504088896340736f
#define PI_F      3.14159265358979323846f
#define NEG_LOG_EPS 69.07755278982137f            // -ln(1e-30)

typedef short bf16x8 __attribute__((ext_vector_type(8)));
typedef float f32x4  __attribute__((ext_vector_type(4)));
typedef unsigned short u16x8 __attribute__((ext_vector_type(8)));

static __device__ __forceinline__ unsigned short f2bf(float f) {
    unsigned int u = __builtin_bit_cast(unsigned int, f);
    u += 0x7fffu + ((u >> 16) & 1u);              // round-to-nearest-even
    return (unsigned short)(u >> 16);
}

// async 16B/lane global -> LDS (LDS dest = wave-uniform base + lane*16)
static __device__ __forceinline__ void gld16(const unsigned short* g, unsigned short* l) {
    __builtin_amdgcn_global_load_lds(
        (const __attribute__((address_space(1))) unsigned int*)g,
        (__attribute__((address_space(3))) unsigned int*)l, 16, 0, 0);
}

// ---------------- kernel 1: normalize embeddings -> bf16 A [1024 x 512] ---
__global__ __launch_bounds__(256) void norm_embed(const float* __restrict__ E,
                                                  unsigned short* __restrict__ Abf) {
    const int b = blockIdx.x;
    const int t = threadIdx.x;
    float2 v = ((const float2*)(E + (size_t)b * D_DIM))[t];
    float ss = v.x * v.x + v.y * v.y;
    #pragma unroll
    for (int off = 1; off < 64; off <<= 1) ss += __shfl_xor(ss, off);
    __shared__ float ws4[4];
    if ((t & 63) == 0) ws4[t >> 6] = ss;
    __syncthreads();
    float inv = rsqrtf(ws4[0] + ws4[1] + ws4[2] + ws4[3]);
    unsigned int packed = (unsigned int)f2bf(v.x * inv) |
                          ((unsigned int)f2bf(v.y * inv) << 16);
    ((unsigned int*)Abf)[(size_t)b * (D_DIM / 2) + t] = packed;
}

// ---------------- kernel 1b: normalize weights -> bf16 [C x 512] ----------
__global__ __launch_bounds__(256) void norm_weight(const float* __restrict__ W,
                                                   unsigned short* __restrict__ Wbf) {
    const int wave = threadIdx.x >> 6;
    const int lane = threadIdx.x & 63;
    const int row = blockIdx.x * 4 + wave;
    if (row >= C_CLASSES) return;
    const float4* src = (const float4*)(W + (size_t)row * D_DIM);
    float4 v0 = src[lane];
    float4 v1 = src[lane + 64];
    float ss = v0.x*v0.x + v0.y*v0.y + v0.z*v0.z + v0.w*v0.w
             + v1.x*v1.x + v1.y*v1.y + v1.z*v1.z + v1.w*v1.w;
    #pragma unroll
    for (int off = 1; off < 64; off <<= 1) ss += __shfl_xor(ss, off);
    float inv = rsqrtf(ss);
    ushort4 o0, o1;
    o0.x = f2bf(v0.x*inv); o0.y = f2bf(v0.y*inv); o0.z = f2bf(v0.z*inv); o0.w = f2bf(v0.w*inv);
    o1.x = f2bf(v1.x*inv); o1.y = f2bf(v1.y*inv); o1.z = f2bf(v1.z*inv); o1.w = f2bf(v1.w*inv);
    ushort4* dst = (ushort4*)(Wbf + (size_t)row * D_DIM);
    dst[lane] = o0;
    dst[lane + 64] = o1;
}

// ---------------- kernel 2: bf16 GEMM (cosine logits) + margin + partial softmax
// grid = dim3(MTILES, NTILES): x (fastest) = m-tile so the 8 blocks sharing a
// W n-tile are dispatched adjacently -> W window stays L3-resident (~13 MB).
// __launch_bounds__(256,1): allow up to 512 unified regs -> no scratch spill.
__global__ __launch_bounds__(256, 1) void gemm_cos(const unsigned short* __restrict__ Abf,
                                                   const unsigned short* __restrict__ Wbf,
                                                   const int* __restrict__ labels,
                                                   float* __restrict__ st,
                                                   float* __restrict__ partial) {
    __shared__ unsigned short As[BM * BK];   // 8 KiB, unpadded (global_load_lds layout)
    __shared__ unsigned short Bs[BN * BK];   // 8 KiB
    __shared__ float rowSum[BM];
    __shared__ int   labs[BM];

    const int tid = threadIdx.x;
    const int m0 = blockIdx.x * BM;
    const int n0 = blockIdx.y * BN;
    if (tid < BM) { labs[tid] = labels[m0 + tid]; rowSum[tid] = 0.f; }

    const int lane = tid & 63;
    const int wave = tid >> 6;
    const int wm = wave & 1, wn = wave >> 1;
    const int l15 = lane & 15, quad = lane >> 4;

    // staging: wave w stages chunks (2w) and (2w+1) of both tiles.
    // chunk c = rows [16c,16c+16); lane i -> row 16c+(i>>2), col 8*(i&3).
    const int rsub = lane >> 2;
    const int cg   = (lane & 3) * 8;
    const int c0 = wave * 2, c1 = wave * 2 + 1;
    const unsigned short* gA0 = Abf + (size_t)(m0 + c0 * 16 + rsub) * D_DIM + cg;
    const unsigned short* gA1 = Abf + (size_t)(m0 + c1 * 16 + rsub) * D_DIM + cg;
    const int bR0 = min(n0 + c0 * 16 + rsub, C_CLASSES - 1);
    const int bR1 = min(n0 + c1 * 16 + rsub, C_CLASSES - 1);
    const unsigned short* gB0 = Wbf + (size_t)bR0 * D_DIM + cg;
    const unsigned short* gB1 = Wbf + (size_t)bR1 * D_DIM + cg;
    unsigned short* lA0 = &As[c0 * 512];    // 1024 B per chunk
    unsigned short* lA1 = &As[c1 * 512];
    unsigned short* lB0 = &Bs[c0 * 512];
    unsigned short* lB1 = &Bs[c1 * 512];

    f32x4 acc[4][4];
    #pragma unroll
    for (int i = 0; i < 4; ++i)
        #pragma unroll
        for (int j = 0; j < 4; ++j)
            acc[i][j] = (f32x4){0.f, 0.f, 0.f, 0.f};

    for (int kk = 0; kk < KITERS; ++kk) {
        __syncthreads();                     // prior frag reads done
        gld16(gA0, lA0); gld16(gA1, lA1);
        gld16(gB0, lB0); gld16(gB1, lB1);
        gA0 += BK; gA1 += BK; gB0 += BK; gB1 += BK;
        __syncthreads();                     // loads visible (vmcnt drained)

        bf16x8 af[4], bfr[4];
        #pragma unroll
        for (int mi = 0; mi < 4; ++mi)
            af[mi] = *(const bf16x8*)&As[(wm * 64 + mi * 16 + l15) * BK + quad * 8];
        #pragma unroll
        for (int ni = 0; ni < 4; ++ni)
            bfr[ni] = *(const bf16x8*)&Bs[(wn * 64 + ni * 16 + l15) * BK + quad * 8];
        #pragma unroll
        for (int mi = 0; mi < 4; ++mi)
            #pragma unroll
            for (int ni = 0; ni < 4; ++ni)
                acc[mi][ni] = __builtin_amdgcn_mfma_f32_16x16x32_bf16(af[mi], bfr[ni], acc[mi][ni], 0, 0, 0);
    }

    // ---- epilogue: clip -> margin at label -> sum exp(s-64) per row ----
    #pragma unroll
    for (int mi = 0; mi < 4; ++mi) {
        #pragma unroll
        for (int r = 0; r < 4; ++r) {
            const int rloc = wm * 64 + mi * 16 + quad * 4 + r;
            const int lab = labs[rloc];
            float part = 0.f;
            #pragma unroll
            for (int ni = 0; ni < 4; ++ni) {
                const int col = n0 + wn * 64 + ni * 16 + l15;
                float cosv = fminf(1.f, fmaxf(-1.f, acc[mi][ni][r]));
                if (col < C_CLASSES) {
                    float s = cosv * 64.0f;
                    if (col == lab) {
                        s = cosf(fminf(acosf(cosv) + 0.5f, PI_F)) * 64.0f;
                        st[m0 + rloc] = s;   // unique writer across grid
                    }
                    part += exp2f((s - 64.0f) * LOG2E);
                }
            }
            part += __shfl_xor(part, 1);
            part += __shfl_xor(part, 2);
            part += __shfl_xor(part, 4);
            part += __shfl_xor(part, 8);
            if (l15 == 0) atomicAdd(&rowSum[rloc], part);
        }
    }
    __syncthreads();
    if (tid < BM) partial[(size_t)blockIdx.y * B_BATCH + m0 + tid] = rowSum[tid];
}

// ---------------- kernel 3: per-row combine + mean loss ----------------
// 16 blocks x 64 threads; lane b reads partial[t*1024+b] -> coalesced.
__global__ __launch_bounds__(64) void reduce_loss(const float* __restrict__ partial,
                                                  const float* __restrict__ st,
                                                  float* __restrict__ out) {
    const int b = blockIdx.x * 64 + threadIdx.x;
    float L = 0.f;
    for (int t = 0; t < NTILES; ++t) L += partial[(size_t)t * B_BATCH + b];
    float logp = st[b] - 64.0f - logf(L);
    float lossb = fminf(-logp, NEG_LOG_EPS) * (1.0f / (float)B_BATCH);
    #pragma unroll
    for (int off = 1; off < 64; off <<= 1) lossb += __shfl_xor(lossb, off);
    if (threadIdx.x == 0) atomicAdd(out, lossb);
}

// ================= fallback (fused, needs only ~4.3 MB ws) =========
#define LDS_STRIDE 40
__global__ __launch_bounds__(256, 1) void gemm_pfc(const unsigned short* __restrict__ Abf,
                                                   const float* __restrict__ W,
                                                   const int* __restrict__ labels,
                                                   float* __restrict__ st,
                                                   float* __restrict__ partial) {
    __shared__ unsigned short As[BM * LDS_STRIDE];
    __shared__ unsigned short Bs[BN * LDS_STRIDE];
    __shared__ float invN[BN];
    __shared__ float rowSum[BM];
    __shared__ float nrmPart[256];
    __shared__ int   labs[BM];

    const int tid = threadIdx.x;
    const int m0 = blockIdx.x * BM;
    const int n0 = blockIdx.y * BN;
    if (tid < BM) { labs[tid] = labels[m0 + tid]; rowSum[tid] = 0.f; }

    const int lane = tid & 63;
    const int wave = tid >> 6;
    const int wm = wave & 1, wn = wave >> 1;
    const int l15 = lane & 15, quad = lane >> 4;

    f32x4 acc[4][4];
    #pragma unroll
    for (int i = 0; i < 4; ++i)
        #pragma unroll
        for (int j = 0; j < 4; ++j)
            acc[i][j] = (f32x4){0.f, 0.f, 0.f, 0.f};

    const int r2 = tid >> 1;
    const int h2 = tid & 1;
    const int bRow = min(n0 + r2, C_CLASSES - 1);
    const float* bBase = W + (size_t)bRow * D_DIM + h2 * 16;
    const unsigned short* aBase = Abf + (size_t)(m0 + r2) * D_DIM + h2 * 16;

    float nrm = 0.f;
    for (int kk = 0; kk < KITERS; ++kk) {
        const int k0 = kk * BK;
        uint4 a0 = ((const uint4*)(aBase + k0))[0];
        uint4 a1 = ((const uint4*)(aBase + k0))[1];
        float4 f0 = ((const float4*)(bBase + k0))[0];
        float4 f1 = ((const float4*)(bBase + k0))[1];
        float4 f2 = ((const float4*)(bBase + k0))[2];
        float4 f3 = ((const float4*)(bBase + k0))[3];
        float fl[16] = {f0.x, f0.y, f0.z, f0.w, f1.x, f1.y, f1.z, f1.w,
                        f2.x, f2.y, f2.z, f2.w, f3.x, f3.y, f3.z, f3.w};
        u16x8 p0, p1;
        #pragma unroll
        for (int i = 0; i < 8; ++i) {
            nrm += fl[i] * fl[i] + fl[i + 8] * fl[i + 8];
            p0[i] = f2bf(fl[i]);
            p1[i] = f2bf(fl[i + 8]);
        }
        __syncthreads();
        *(uint4*)&As[r2 * LDS_STRIDE + h2 * 16]     = a0;
        *(uint4*)&As[r2 * LDS_STRIDE + h2 * 16 + 8] = a1;
        *(u16x8*)&Bs[r2 * LDS_STRIDE + h2 * 16]     = p0;
        *(u16x8*)&Bs[r2 * LDS_STRIDE + h2 * 16 + 8] = p1;
        __syncthreads();
        bf16x8 af[4], bfr[4];
        #pragma unroll
        for (int mi = 0; mi < 4; ++mi)
            af[mi] = *(const bf16x8*)&As[(wm * 64 + mi * 16 + l15) * LDS_STRIDE + quad * 8];
        #pragma unroll
        for (int ni = 0; ni < 4; ++ni)
            bfr[ni] = *(const bf16x8*)&Bs[(wn * 64 + ni * 16 + l15) * LDS_STRIDE + quad * 8];
        #pragma unroll
        for (int mi = 0; mi < 4; ++mi)
            #pragma unroll
            for (int ni = 0; ni < 4; ++ni)
                acc[mi][ni] = __builtin_amdgcn_mfma_f32_16x16x32_bf16(af[mi], bfr[ni], acc[mi][ni], 0, 0, 0);
    }
    nrmPart[tid] = nrm;
    __syncthreads();
    if (tid < BN) invN[tid] = rsqrtf(nrmPart[2 * tid] + nrmPart[2 * tid + 1]);
    __syncthreads();
    float rn[4];
    #pragma unroll
    for (int ni = 0; ni < 4; ++ni) rn[ni] = invN[wn * 64 + ni * 16 + l15];
    #pragma unroll
    for (int mi = 0; mi < 4; ++mi) {
        #pragma unroll
        for (int r = 0; r < 4; ++r) {
            const int rloc = wm * 64 + mi * 16 + quad * 4 + r;
            const int lab = labs[rloc];
            float part = 0.f;
            #pragma unroll
            for (int ni = 0; ni < 4; ++ni) {
                const int col = n0 + wn * 64 + ni * 16 + l15;
                float cosv = acc[mi][ni][r] * rn[ni];
                cosv = fminf(1.f, fmaxf(-1.f, cosv));
                if (col < C_CLASSES) {
                    float s = cosv * 64.0f;
                    if (col == lab) {
                        s = cosf(fminf(acosf(cosv) + 0.5f, PI_F)) * 64.0f;
                        st[m0 + rloc] = s;
                    }
                    part += exp2f((s - 64.0f) * LOG2E);
                }
            }
            part += __shfl_xor(part, 1);
            part += __shfl_xor(part, 2);
            part += __shfl_xor(part, 4);
            part += __shfl_xor(part, 8);
            if (l15 == 0) atomicAdd(&rowSum[rloc], part);
        }
    }
    __syncthreads();
    if (tid < BM) partial[(size_t)blockIdx.y * B_BATCH + m0 + tid] = rowSum[tid];
}

extern "C" void kernel_launch(void* const* d_in, const int* in_sizes, int n_in,
                              void* d_out, int out_size, void* d_ws, size_t ws_size,
                              hipStream_t stream) {
    const float* emb = (const float*)d_in[0];
    const float* wgt = (const float*)d_in[1];
    const int*   lab = (const int*)d_in[2];
    float* out = (float*)d_out;
    char* ws = (char*)d_ws;

    const size_t WBF_B  = (size_t)C_CLASSES * D_DIM * 2;  // 102,400,000
    const size_t ABF_B  = (size_t)B_BATCH * D_DIM * 2;    // 1,048,576
    const size_t ST_B   = 4096;
    const size_t PART_B = (size_t)NTILES * B_BATCH * 4;   // 3,203,072

    hipMemsetAsync(d_out, 0, sizeof(float), stream);

    if (ws_size >= WBF_B + ABF_B + ST_B + PART_B) {
        unsigned short* Wbf = (unsigned short*)ws;
        unsigned short* Abf = (unsigned short*)(ws + WBF_B);
        float* st      = (float*)(ws + WBF_B + ABF_B);
        float* partial = (float*)(ws + WBF_B + ABF_B + ST_B);
        norm_embed<<<B_BATCH, 256, 0, stream>>>(emb, Abf);
        norm_weight<<<(C_CLASSES + 3) / 4, 256, 0, stream>>>(wgt, Wbf);
        gemm_cos<<<dim3(MTILES, NTILES), 256, 0, stream>>>(Abf, Wbf, lab, st, partial);
        reduce_loss<<<16, 64, 0, stream>>>(partial, st, out);
    } else {
        unsigned short* Abf = (unsigned short*)ws;
        float* st      = (float*)(ws + ABF_B);
        float* partial = (float*)(ws + ABF_B + ST_B);
        norm_embed<<<B_BATCH, 256, 0, stream>>>(emb, Abf);
        gemm_pfc<<<dim3(MTILES, NTILES), 256, 0, stream>>>(Abf, wgt, lab, st, partial);
        reduce_loss<<<16, 64, 0, stream>>>(partial, st, out);
    }
}

// Round 4
// 498.463 us; speedup vs baseline: 3.4242x; 2.8973x over previous
//
#include <hip/hip_runtime.h>
#include <hip/hip_bf16.h>
#include <math.h>
#include <stdint.h>

#define B_BATCH   1024
#define D_DIM     512
#define C_CLASSES 100000
#define BM        128
#define BN        128
#define BK        32
#define KITERS    (D_DIM / BK)                    // 16
#define MTILES    (B_BATCH / BM)                  // 8
#define NTILES    ((C_CLASSES + BN - 1) / BN)     // 782
#define LOG2E     1.44269504088896340736f
#define COSM      0.87758256189037276f            // cos(0.5)
#define SINM      0.47942553860420301f            // sin(0.5)
#define NEG_LOG_EPS 69.07755278982137f            // -ln(1e-30)

typedef short bf16x8 __attribute__((ext_vector_type(8)));
typedef float f32x4  __attribute__((ext_vector_type(4)));

static __device__ __forceinline__ unsigned short f2bf(float f) {
    unsigned int u = __builtin_bit_cast(unsigned int, f);
    u += 0x7fffu + ((u >> 16) & 1u);              // round-to-nearest-even
    return (unsigned short)(u >> 16);
}

// async 16B/lane global -> LDS (LDS dest = wave-uniform base + lane*16)
static __device__ __forceinline__ void gld16(const unsigned short* g, unsigned short* l) {
    __builtin_amdgcn_global_load_lds(
        (const __attribute__((address_space(1))) unsigned int*)g,
        (__attribute__((address_space(3))) unsigned int*)l, 16, 0, 0);
}

// ---------------- kernel 1: normalize embeddings -> bf16 A [1024 x 512] ---
__global__ __launch_bounds__(256) void norm_embed(const float* __restrict__ E,
                                                  unsigned short* __restrict__ Abf) {
    const int b = blockIdx.x;
    const int t = threadIdx.x;
    float2 v = ((const float2*)(E + (size_t)b * D_DIM))[t];
    float ss = v.x * v.x + v.y * v.y;
    #pragma unroll
    for (int off = 1; off < 64; off <<= 1) ss += __shfl_xor(ss, off);
    __shared__ float ws4[4];
    if ((t & 63) == 0) ws4[t >> 6] = ss;
    __syncthreads();
    float inv = rsqrtf(ws4[0] + ws4[1] + ws4[2] + ws4[3]);
    unsigned int packed = (unsigned int)f2bf(v.x * inv) |
                          ((unsigned int)f2bf(v.y * inv) << 16);
    ((unsigned int*)Abf)[(size_t)b * (D_DIM / 2) + t] = packed;
}

// ---------------- kernel 1b: normalize weights -> bf16 [C x 512] ----------
__global__ __launch_bounds__(256) void norm_weight(const float* __restrict__ W,
                                                   unsigned short* __restrict__ Wbf) {
    const int wave = threadIdx.x >> 6;
    const int lane = threadIdx.x & 63;
    const int row = blockIdx.x * 4 + wave;
    if (row >= C_CLASSES) return;
    const float4* src = (const float4*)(W + (size_t)row * D_DIM);
    float4 v0 = src[lane];
    float4 v1 = src[lane + 64];
    float ss = v0.x*v0.x + v0.y*v0.y + v0.z*v0.z + v0.w*v0.w
             + v1.x*v1.x + v1.y*v1.y + v1.z*v1.z + v1.w*v1.w;
    #pragma unroll
    for (int off = 1; off < 64; off <<= 1) ss += __shfl_xor(ss, off);
    float inv = rsqrtf(ss);
    ushort4 o0, o1;
    o0.x = f2bf(v0.x*inv); o0.y = f2bf(v0.y*inv); o0.z = f2bf(v0.z*inv); o0.w = f2bf(v0.w*inv);
    o1.x = f2bf(v1.x*inv); o1.y = f2bf(v1.y*inv); o1.z = f2bf(v1.z*inv); o1.w = f2bf(v1.w*inv);
    ushort4* dst = (ushort4*)(Wbf + (size_t)row * D_DIM);
    dst[lane] = o0;
    dst[lane + 64] = o1;
}

// epilogue per-element: clip, ArcFace margin (no libm: cos(th+m) identity),
// returns exp(s - 64)
static __device__ __forceinline__ float epi_term(float accv, int col, int lab,
                                                 float* __restrict__ st, int srow) {
    float c = fminf(1.f, fmaxf(-1.f, accv));
    if (col >= C_CLASSES) return 0.f;
    float s = c * 64.0f;
    if (col == lab) {
        float sn = sqrtf(fmaxf(0.f, 1.f - c * c));
        float nm = c * COSM - sn * SINM;          // cos(theta + m)
        if (c < -COSM) nm = -1.f;                 // theta + m > pi -> cos(pi)
        s = nm * 64.0f;
        st[srow] = s;                             // unique writer across grid
    }
    return exp2f((s - 64.0f) * LOG2E);
}

// ---------------- kernel 2: bf16 GEMM (cosine logits) + margin + partial softmax
// grid = dim3(MTILES, NTILES): x fastest = m-tile -> blocks sharing a W-tile
// are adjacent in dispatch order (L3-resident W window).
// All accumulators/fragments are individually named scalars: nothing for
// promote-alloca to demote to scratch (round-3 post-mortem: acc[4][4] array
// lived in scratch -> 6.4 GB of phantom HBM writes).
__global__ __launch_bounds__(256) void gemm_cos(const unsigned short* __restrict__ Abf,
                                                const unsigned short* __restrict__ Wbf,
                                                const int* __restrict__ labels,
                                                float* __restrict__ st,
                                                float* __restrict__ partial) {
    __shared__ unsigned short As[BM * BK];   // 8 KiB, unpadded (global_load_lds layout)
    __shared__ unsigned short Bs[BN * BK];   // 8 KiB
    __shared__ float rowSum[BM];
    __shared__ int   labs[BM];

    const int tid = threadIdx.x;
    const int m0 = blockIdx.x * BM;
    const int n0 = blockIdx.y * BN;
    if (tid < BM) { labs[tid] = labels[m0 + tid]; rowSum[tid] = 0.f; }

    const int lane = tid & 63;
    const int wave = tid >> 6;
    const int wm = wave & 1, wn = wave >> 1;
    const int l15 = lane & 15, quad = lane >> 4;

    // staging: wave w stages chunks (2w),(2w+1); chunk c = tile rows [16c,16c+16)
    const int rsub = lane >> 2;
    const int cg   = (lane & 3) * 8;
    const int c0 = wave * 2, c1 = wave * 2 + 1;
    const unsigned short* gA0 = Abf + (size_t)(m0 + c0 * 16 + rsub) * D_DIM + cg;
    const unsigned short* gA1 = Abf + (size_t)(m0 + c1 * 16 + rsub) * D_DIM + cg;
    const int bR0 = min(n0 + c0 * 16 + rsub, C_CLASSES - 1);
    const int bR1 = min(n0 + c1 * 16 + rsub, C_CLASSES - 1);
    const unsigned short* gB0 = Wbf + (size_t)bR0 * D_DIM + cg;
    const unsigned short* gB1 = Wbf + (size_t)bR1 * D_DIM + cg;
    unsigned short* lA0 = &As[c0 * 512];
    unsigned short* lA1 = &As[c1 * 512];
    unsigned short* lB0 = &Bs[c0 * 512];
    unsigned short* lB1 = &Bs[c1 * 512];

    const f32x4 z = (f32x4){0.f, 0.f, 0.f, 0.f};
    f32x4 a00 = z, a01 = z, a02 = z, a03 = z;
    f32x4 a10 = z, a11 = z, a12 = z, a13 = z;
    f32x4 a20 = z, a21 = z, a22 = z, a23 = z;
    f32x4 a30 = z, a31 = z, a32 = z, a33 = z;

    for (int kk = 0; kk < KITERS; ++kk) {
        __syncthreads();                     // prior frag reads done
        gld16(gA0, lA0); gld16(gA1, lA1);
        gld16(gB0, lB0); gld16(gB1, lB1);
        gA0 += BK; gA1 += BK; gB0 += BK; gB1 += BK;
        __syncthreads();                     // loads visible

        const int aro = (wm * 64 + l15) * BK + quad * 8;
        const int bro = (wn * 64 + l15) * BK + quad * 8;
        bf16x8 af0 = *(const bf16x8*)&As[aro];
        bf16x8 af1 = *(const bf16x8*)&As[aro + 16 * BK];
        bf16x8 af2 = *(const bf16x8*)&As[aro + 32 * BK];
        bf16x8 af3 = *(const bf16x8*)&As[aro + 48 * BK];
        bf16x8 bf0 = *(const bf16x8*)&Bs[bro];
        bf16x8 bf1 = *(const bf16x8*)&Bs[bro + 16 * BK];
        bf16x8 bf2 = *(const bf16x8*)&Bs[bro + 32 * BK];
        bf16x8 bf3 = *(const bf16x8*)&Bs[bro + 48 * BK];

        a00 = __builtin_amdgcn_mfma_f32_16x16x32_bf16(af0, bf0, a00, 0, 0, 0);
        a01 = __builtin_amdgcn_mfma_f32_16x16x32_bf16(af0, bf1, a01, 0, 0, 0);
        a02 = __builtin_amdgcn_mfma_f32_16x16x32_bf16(af0, bf2, a02, 0, 0, 0);
        a03 = __builtin_amdgcn_mfma_f32_16x16x32_bf16(af0, bf3, a03, 0, 0, 0);
        a10 = __builtin_amdgcn_mfma_f32_16x16x32_bf16(af1, bf0, a10, 0, 0, 0);
        a11 = __builtin_amdgcn_mfma_f32_16x16x32_bf16(af1, bf1, a11, 0, 0, 0);
        a12 = __builtin_amdgcn_mfma_f32_16x16x32_bf16(af1, bf2, a12, 0, 0, 0);
        a13 = __builtin_amdgcn_mfma_f32_16x16x32_bf16(af1, bf3, a13, 0, 0, 0);
        a20 = __builtin_amdgcn_mfma_f32_16x16x32_bf16(af2, bf0, a20, 0, 0, 0);
        a21 = __builtin_amdgcn_mfma_f32_16x16x32_bf16(af2, bf1, a21, 0, 0, 0);
        a22 = __builtin_amdgcn_mfma_f32_16x16x32_bf16(af2, bf2, a22, 0, 0, 0);
        a23 = __builtin_amdgcn_mfma_f32_16x16x32_bf16(af2, bf3, a23, 0, 0, 0);
        a30 = __builtin_amdgcn_mfma_f32_16x16x32_bf16(af3, bf0, a30, 0, 0, 0);
        a31 = __builtin_amdgcn_mfma_f32_16x16x32_bf16(af3, bf1, a31, 0, 0, 0);
        a32 = __builtin_amdgcn_mfma_f32_16x16x32_bf16(af3, bf2, a32, 0, 0, 0);
        a33 = __builtin_amdgcn_mfma_f32_16x16x32_bf16(af3, bf3, a33, 0, 0, 0);
    }

    const int colbase = n0 + wn * 64 + l15;

    #define EPIROW(A0, A1, A2, A3, MI)                                         \
    {                                                                          \
        _Pragma("unroll")                                                      \
        for (int r = 0; r < 4; ++r) {                                          \
            const int rloc = wm * 64 + (MI) * 16 + quad * 4 + r;               \
            const int lab = labs[rloc];                                        \
            float part = 0.f;                                                  \
            part += epi_term((A0)[r], colbase,      lab, st, m0 + rloc);       \
            part += epi_term((A1)[r], colbase + 16, lab, st, m0 + rloc);       \
            part += epi_term((A2)[r], colbase + 32, lab, st, m0 + rloc);       \
            part += epi_term((A3)[r], colbase + 48, lab, st, m0 + rloc);       \
            part += __shfl_xor(part, 1);                                       \
            part += __shfl_xor(part, 2);                                       \
            part += __shfl_xor(part, 4);                                       \
            part += __shfl_xor(part, 8);                                       \
            if (l15 == 0) atomicAdd(&rowSum[rloc], part);                      \
        }                                                                      \
    }

    EPIROW(a00, a01, a02, a03, 0)
    EPIROW(a10, a11, a12, a13, 1)
    EPIROW(a20, a21, a22, a23, 2)
    EPIROW(a30, a31, a32, a33, 3)
    #undef EPIROW

    __syncthreads();
    if (tid < BM) partial[(size_t)blockIdx.y * B_BATCH + m0 + tid] = rowSum[tid];
}

// ---------------- kernel 3: per-row combine + mean loss ----------------
__global__ __launch_bounds__(64) void reduce_loss(const float* __restrict__ partial,
                                                  const float* __restrict__ st,
                                                  float* __restrict__ out) {
    const int b = blockIdx.x * 64 + threadIdx.x;
    float L = 0.f;
    for (int t = 0; t < NTILES; ++t) L += partial[(size_t)t * B_BATCH + b];
    float logp = st[b] - 64.0f - logf(L);
    float lossb = fminf(-logp, NEG_LOG_EPS) * (1.0f / (float)B_BATCH);
    #pragma unroll
    for (int off = 1; off < 64; off <<= 1) lossb += __shfl_xor(lossb, off);
    if (threadIdx.x == 0) atomicAdd(out, lossb);
}

extern "C" void kernel_launch(void* const* d_in, const int* in_sizes, int n_in,
                              void* d_out, int out_size, void* d_ws, size_t ws_size,
                              hipStream_t stream) {
    const float* emb = (const float*)d_in[0];
    const float* wgt = (const float*)d_in[1];
    const int*   lab = (const int*)d_in[2];
    float* out = (float*)d_out;
    char* ws = (char*)d_ws;

    const size_t WBF_B = (size_t)C_CLASSES * D_DIM * 2;  // 102,400,000
    const size_t ABF_B = (size_t)B_BATCH * D_DIM * 2;    // 1,048,576

    unsigned short* Wbf = (unsigned short*)ws;
    unsigned short* Abf = (unsigned short*)(ws + WBF_B);
    float* st      = (float*)(ws + WBF_B + ABF_B);
    float* partial = (float*)(ws + WBF_B + ABF_B + 4096);

    hipMemsetAsync(d_out, 0, sizeof(float), stream);
    norm_embed<<<B_BATCH, 256, 0, stream>>>(emb, Abf);
    norm_weight<<<(C_CLASSES + 3) / 4, 256, 0, stream>>>(wgt, Wbf);
    gemm_cos<<<dim3(MTILES, NTILES), 256, 0, stream>>>(Abf, Wbf, lab, st, partial);
    reduce_loss<<<16, 64, 0, stream>>>(partial, st, out);
}